// Round 2
// baseline (900.481 us; speedup 1.0000x reference)
//
#include <hip/hip_runtime.h>

// Problem constants
constexpr int BQ = 512, CQ = 200, EQ = 128, CV = 384, KD = 384;
constexpr int M = BQ * CQ;                  // 102400 rows
constexpr int BM = 64, BN = 384, BK = 64;   // fused GEMM tile: full CV per block

using frag = __attribute__((ext_vector_type(8))) short;  // 8 bf16 (4 VGPRs)
using facc = __attribute__((ext_vector_type(4))) float;  // 4 f32 acc

// round-to-nearest-even f32 -> bf16 bits (inputs finite)
__device__ __forceinline__ short f2b(float f) {
    unsigned int u = __float_as_uint(f);
    u = (u + 0x7fffu + ((u >> 16) & 1u)) >> 16;
    return (short)u;
}
__device__ __forceinline__ unsigned pack2(float lo, float hi) {
    return (unsigned)(unsigned short)f2b(lo) | ((unsigned)(unsigned short)f2b(hi) << 16);
}

__device__ __forceinline__ float tanh_fast(float x) {
    float e = __expf(2.0f * x);
    return 1.0f - 2.0f * __builtin_amdgcn_rcpf(e + 1.0f);
}

// async global->LDS, 16B per lane; LDS dst is wave-uniform base + lane*16
__device__ __forceinline__ void async16(const void* g, void* l) {
    __builtin_amdgcn_global_load_lds(
        (const __attribute__((address_space(1))) void*)g,
        (__attribute__((address_space(3))) void*)l, 16, 0, 0);
}

// ---- K0: W f32 -> bf16 ----
__global__ __launch_bounds__(256) void conv_w(const float* __restrict__ W, short* __restrict__ Wb) {
    int i = (blockIdx.x * 256 + threadIdx.x) * 4;
    float4 v = *(const float4*)(W + i);
    uint2 o;
    o.x = pack2(v.x, v.y);
    o.y = pack2(v.z, v.w);
    *(uint2*)(Wb + i) = o;
}

// ---- K1: fused gather + convert + GEMM h = tanh(ctx @ Wb^T) + full scores ----
// grid = M/BM = 1600 blocks, 512 threads (8 waves as 2m x 4n; wave tile 32x96)
// Gathers are software-pipelined: slice for step kc+1 loads during kc's MFMA.
__global__ __launch_bounds__(512, 4) void fused_gemm(
    const int* __restrict__ starts, const int* __restrict__ paths, const int* __restrict__ ends,
    const float* __restrict__ node_emb, const float* __restrict__ path_emb,
    const short* __restrict__ Wb, const float* __restrict__ a,
    short* __restrict__ h_out, float* __restrict__ scores)
{
    __shared__ short As[BM * BK];  // 8 KB, XOR-swizzled 16B chunks
    __shared__ short Bs[BN * BK];  // 48 KB, same swizzle (56 KB -> 2 blocks/CU)

    const int tid = threadIdx.x;
    const int m0 = blockIdx.x * BM;
    const int wave = tid >> 6, lane = tid & 63;
    const int wm = (wave >> 2) * 32;   // {0,32}
    const int wn = (wave & 3) * 96;    // {0,96,192,288}
    const int l15 = lane & 15, quad = lane >> 4;

    // A gather ownership: 8 threads per row, each owns 16 f32 (64 B) per table
    const int tr = tid >> 3, part = tid & 7;
    const int grow = m0 + tr;
    const float* bS = node_emb + (size_t)starts[grow] * EQ + part * 16;
    const float* bP = path_emb + (size_t)paths[grow] * EQ + part * 16;
    const float* bE = node_emb + (size_t)ends[grow]  * EQ + part * 16;
    const int hi = part >> 2;          // which K-half of the segment this thread owns
    // LDS write offsets (shorts): chunk c16 stored at slot c16 ^ (row&7)
    const int c16a = (part & 3) * 2, c16b = c16a + 1;
    const int wa0 = tr * BK + ((c16a ^ (tr & 7)) * 8);
    const int wa1 = tr * BK + ((c16b ^ (tr & 7)) * 8);

    // B staging via global_load_lds: pre-swizzled global source, linear LDS dest
    const int sr = lane >> 3;                  // row-in-8-group
    const int scb = ((lane & 7) ^ sr) * 16;    // swizzled 16B chunk in 128B row
    const char* cB = (const char*)Wb;

    facc acc[2][6];
#pragma unroll
    for (int i = 0; i < 2; ++i)
#pragma unroll
        for (int j = 0; j < 6; ++j) acc[i][j] = (facc){0.f, 0.f, 0.f, 0.f};

    // pipelined gather registers (one 64B slice)
    float4 v0, v1, v2, v3;
#define LOADSEG(p) { const float4* q = (const float4*)(p); v0 = q[0]; v1 = q[1]; v2 = q[2]; v3 = q[3]; }
    if (!hi) LOADSEG(bS)               // prologue: kc=0 actives

#pragma unroll
    for (int kc = 0; kc < 6; ++kc) {
        __syncthreads();   // previous tile's readers done
        // B slice [384 x 64]: 48 x 1KB async copies, 6 per wave
#pragma unroll
        for (int t = 0; t < 6; ++t) {
            const int r0 = wave * 48 + t * 8;
            async16(cB + ((size_t)(r0 + sr) * KD + kc * BK) * 2 + scb, &Bs[r0 * BK]);
        }
        // A slice: active half-threads convert staged regs, swizzled ds_write
        if (hi == (kc & 1)) {
            uint4 c0, c1;
            c0.x = pack2(v0.x, v0.y); c0.y = pack2(v0.z, v0.w);
            c0.z = pack2(v1.x, v1.y); c0.w = pack2(v1.z, v1.w);
            c1.x = pack2(v2.x, v2.y); c1.y = pack2(v2.z, v2.w);
            c1.z = pack2(v3.x, v3.y); c1.w = pack2(v3.z, v3.w);
            *(uint4*)&As[wa0] = c0;
            *(uint4*)&As[wa1] = c1;
        }
        __syncthreads();   // drains vmcnt (async16) + lgkm (ds_write)

        // prefetch gather slice for kc+1 (hides under MFMA below)
        if (kc == 0) { if (hi)  LOADSEG(bS) }
        else if (kc == 1) { if (!hi) LOADSEG(bP) }
        else if (kc == 2) { if (hi)  LOADSEG(bP) }
        else if (kc == 3) { if (!hi) LOADSEG(bE) }
        else if (kc == 4) { if (hi)  LOADSEG(bE) }

#pragma unroll
        for (int ks = 0; ks < 2; ++ks) {
            const int co = ((ks * 4 + quad) ^ (l15 & 7)) * 8;
            frag af[2], bf[6];
#pragma unroll
            for (int i = 0; i < 2; ++i)
                af[i] = *(const frag*)&As[(wm + i * 16 + l15) * BK + co];
#pragma unroll
            for (int j = 0; j < 6; ++j)
                bf[j] = *(const frag*)&Bs[(wn + j * 16 + l15) * BK + co];
#pragma unroll
            for (int i = 0; i < 2; ++i)
#pragma unroll
                for (int j = 0; j < 6; ++j)
                    acc[i][j] = __builtin_amdgcn_mfma_f32_16x16x32_bf16(af[i], bf[j], acc[i][j], 0, 0, 0);
        }
    }
#undef LOADSEG

    // ---- epilogue: tanh, store h bf16, full per-row score via cross-wave reduce
    __syncthreads();                 // all LDS reads done; reuse As as f32 scratch
    float* sp = (float*)As;          // [4 n-wave slabs][64 rows] = 1 KB

    float av[6];
#pragma unroll
    for (int j = 0; j < 6; ++j) av[j] = a[wn + j * 16 + l15];

#pragma unroll
    for (int i = 0; i < 2; ++i) {
        float sct[4] = {0.f, 0.f, 0.f, 0.f};
#pragma unroll
        for (int j = 0; j < 6; ++j) {
            const int col = wn + j * 16 + l15;
#pragma unroll
            for (int r = 0; r < 4; ++r) {
                const int rowo = m0 + wm + i * 16 + quad * 4 + r;
                const float hv = tanh_fast(acc[i][j][r]);
                h_out[(size_t)rowo * CV + col] = f2b(hv);
                sct[r] = fmaf(hv, av[j], sct[r]);
            }
        }
#pragma unroll
        for (int r = 0; r < 4; ++r) {
            float v = sct[r];
            v += __shfl_xor(v, 1);
            v += __shfl_xor(v, 2);
            v += __shfl_xor(v, 4);
            v += __shfl_xor(v, 8);
            if (l15 == 0)
                sp[(wave & 3) * BM + wm + i * 16 + quad * 4 + r] = v;
        }
    }
    __syncthreads();
    if (tid < BM)
        scores[m0 + tid] = sp[tid] + sp[BM + tid] + sp[2 * BM + tid] + sp[3 * BM + tid];
}

// ---- K2: per-batch softmax over C=200 + attention-weighted sum -> out[b][v] ----
__global__ __launch_bounds__(256) void c2v_attn_out(
    const float* __restrict__ scores, const short* __restrict__ h,
    float* __restrict__ out)
{
    __shared__ float attn_s[CQ];
    __shared__ float wred[4];

    const int b = blockIdx.x;
    const int t = threadIdx.x;
    const int lane = t & 63, wv = t >> 6;

    float s = -1e30f;
    if (t < CQ) s = scores[b * CQ + t];
    float m = s;
#pragma unroll
    for (int o = 32; o; o >>= 1) m = fmaxf(m, __shfl_xor(m, o));
    if (lane == 0) wred[wv] = m;
    __syncthreads();
    const float gm = fmaxf(fmaxf(wred[0], wred[1]), fmaxf(wred[2], wred[3]));
    __syncthreads();

    float e = (t < CQ) ? __expf(s - gm) : 0.0f;
    float sum = e;
#pragma unroll
    for (int o = 32; o; o >>= 1) sum += __shfl_xor(sum, o);
    if (lane == 0) wred[wv] = sum;
    __syncthreads();
    const float gs = wred[0] + wred[1] + wred[2] + wred[3];
    if (t < CQ) attn_s[t] = e / gs;
    __syncthreads();

    if (t < 192) {
        const short* hp = h + (size_t)b * CQ * CV + 2 * t;
        float a0 = 0.f, a1 = 0.f;
#pragma unroll 4
        for (int c = 0; c < CQ; ++c) {
            unsigned int u = *(const unsigned int*)hp;
            hp += CV;
            const float w = attn_s[c];
            a0 = fmaf(__uint_as_float(u << 16), w, a0);
            a1 = fmaf(__uint_as_float(u & 0xffff0000u), w, a1);
        }
        out[b * CV + 2 * t]     = a0;
        out[b * CV + 2 * t + 1] = a1;
    }
}

extern "C" void kernel_launch(void* const* d_in, const int* in_sizes, int n_in,
                              void* d_out, int out_size, void* d_ws, size_t ws_size,
                              hipStream_t stream) {
    const int*   starts   = (const int*)d_in[0];
    const int*   paths    = (const int*)d_in[1];
    const int*   ends     = (const int*)d_in[2];
    // d_in[3] = masks: unused (as in reference)
    const float* node_emb = (const float*)d_in[4];
    const float* path_emb = (const float*)d_in[5];
    const float* W        = (const float*)d_in[6];
    const float* a        = (const float*)d_in[7];
    float* out = (float*)d_out;

    // ws layout: h bf16 [M*CV] | Wb bf16 [CV*KD] | scores f32 [M]
    char* p = (char*)d_ws;
    short* h_ws = (short*)p;  p += (size_t)M * CV * sizeof(short);
    short* Wb   = (short*)p;  p += (size_t)CV * KD * sizeof(short);
    float* scores = (float*)p;

    conv_w<<<(CV * KD) / 1024, 256, 0, stream>>>(W, Wb);
    fused_gemm<<<M / BM, 512, 0, stream>>>(starts, paths, ends, node_emb, path_emb,
                                           Wb, a, h_ws, scores);
    c2v_attn_out<<<BQ, 256, 0, stream>>>(scores, h_ws, out);
}

// Round 3
// 774.696 us; speedup vs baseline: 1.1624x; 1.1624x over previous
//
#include <hip/hip_runtime.h>

// Problem constants
constexpr int BQ = 512, CQ = 200, EQ = 128, CV = 384, KD = 384;
constexpr int M = BQ * CQ;
constexpr int MR = 208;   // padded rows per batch = 13 mfma m-tiles

using frag = __attribute__((ext_vector_type(8))) short;  // 8 bf16 (4 VGPRs)
using facc = __attribute__((ext_vector_type(4))) float;  // 4 f32 acc

// round-to-nearest-even f32 -> bf16 bits (inputs finite)
__device__ __forceinline__ short f2b(float f) {
    unsigned int u = __float_as_uint(f);
    u = (u + 0x7fffu + ((u >> 16) & 1u)) >> 16;
    return (short)u;
}
__device__ __forceinline__ unsigned pack2(float lo, float hi) {
    return (unsigned)(unsigned short)f2b(lo) | ((unsigned)(unsigned short)f2b(hi) << 16);
}

__device__ __forceinline__ float tanh_fast(float x) {
    float e = __expf(2.0f * x);
    return 1.0f - 2.0f * __builtin_amdgcn_rcpf(e + 1.0f);
}

// ---- K0: W f32 -> bf16 ----
__global__ __launch_bounds__(256) void conv_w(const float* __restrict__ W, short* __restrict__ Wb) {
    int i = (blockIdx.x * 256 + threadIdx.x) * 4;
    float4 v = *(const float4*)(W + i);
    uint2 o;
    o.x = pack2(v.x, v.y);
    o.y = pack2(v.z, v.w);
    *(uint2*)(Wb + i) = o;
}

// ---- K1: fully fused per-batch kernel ----
// grid = 512 blocks (one batch each), 512 threads = 8 waves, each wave owns 48 cols.
// h lives entirely in accumulators (13 m-frags x 3 n-frags); only out[b][384] hits HBM.
__global__ __launch_bounds__(512, 2) void fused_all(
    const int* __restrict__ starts, const int* __restrict__ paths, const int* __restrict__ ends,
    const float* __restrict__ node_emb, const float* __restrict__ path_emb,
    const short* __restrict__ Wb, const float* __restrict__ a_vec,
    float* __restrict__ out)
{
    __shared__ short As[2][MR * 64];   // 52 KB: double-buffered 64-K slice of ctx, bf16, swizzled
    __shared__ float sp[8][MR];        // per-wave score partials
    __shared__ float score_s[MR];
    __shared__ float attn_s[MR];
    __shared__ float red_s[2];

    const int tid = threadIdx.x, b = blockIdx.x;
    const int wave = tid >> 6, lane = tid & 63;
    const int wn = wave * 48;
    const int l15 = lane & 15, quad = lane >> 4;

    // ---- staging identity: 2 threads per padded row, 32 f32 (128 B) each
    const int tr = tid >> 1, half = tid & 1;
    const bool stg = (tid < 2 * MR);
    const int grow = b * CQ + (tr < CQ ? tr : CQ - 1);   // clamp padded rows
    const float* bS = node_emb;
    const float* bP = path_emb;
    const float* bE = node_emb;
    if (stg) {
        bS = node_emb + (size_t)starts[grow] * EQ + half * 32;
        bP = path_emb + (size_t)paths[grow] * EQ + half * 32;
        bE = node_emb + (size_t)ends[grow]  * EQ + half * 32;
    }
    const int wbase = tr * 64;     // row base (shorts)
    const int rw = tr & 7;         // swizzle key

    float4 s0, s1, s2, s3, s4, s5, s6, s7;   // staged 32 f32, live across MFMA phase

#define ISSUE(kc_) {                                                         \
        const float* sb_ = ((kc_) < 2) ? bS : (((kc_) < 4) ? bP : bE);       \
        const float4* q_ = (const float4*)(sb_ + ((kc_) & 1) * 64);          \
        s0 = q_[0]; s1 = q_[1]; s2 = q_[2]; s3 = q_[3];                      \
        s4 = q_[4]; s5 = q_[5]; s6 = q_[6]; s7 = q_[7];                      \
    }
#define COMMIT(buf_) {                                                       \
        uint4 u_;                                                            \
        u_.x = pack2(s0.x, s0.y); u_.y = pack2(s0.z, s0.w);                  \
        u_.z = pack2(s1.x, s1.y); u_.w = pack2(s1.z, s1.w);                  \
        *(uint4*)&As[buf_][wbase + ((half * 4 + 0) ^ rw) * 8] = u_;          \
        u_.x = pack2(s2.x, s2.y); u_.y = pack2(s2.z, s2.w);                  \
        u_.z = pack2(s3.x, s3.y); u_.w = pack2(s3.z, s3.w);                  \
        *(uint4*)&As[buf_][wbase + ((half * 4 + 1) ^ rw) * 8] = u_;          \
        u_.x = pack2(s4.x, s4.y); u_.y = pack2(s4.z, s4.w);                  \
        u_.z = pack2(s5.x, s5.y); u_.w = pack2(s5.z, s5.w);                  \
        *(uint4*)&As[buf_][wbase + ((half * 4 + 2) ^ rw) * 8] = u_;          \
        u_.x = pack2(s6.x, s6.y); u_.y = pack2(s6.z, s6.w);                  \
        u_.z = pack2(s7.x, s7.y); u_.w = pack2(s7.z, s7.w);                  \
        *(uint4*)&As[buf_][wbase + ((half * 4 + 3) ^ rw) * 8] = u_;          \
    }

    facc acc[13][3];
#pragma unroll
    for (int m = 0; m < 13; ++m)
#pragma unroll
        for (int j = 0; j < 3; ++j) acc[m][j] = (facc){0.f, 0.f, 0.f, 0.f};

    // prologue: stage slice 0
    if (stg) { ISSUE(0); COMMIT(0); }
    __syncthreads();

#pragma unroll
    for (int kc = 0; kc < 6; ++kc) {
        // issue next slice's gathers early: HBM latency hides under MFMA below
        if (kc < 5 && stg) ISSUE(kc + 1);
        const int buf = kc & 1;
#pragma unroll
        for (int ks = 0; ks < 2; ++ks) {
            frag bf[3];
#pragma unroll
            for (int j = 0; j < 3; ++j)
                bf[j] = *(const frag*)(Wb + (size_t)(wn + j * 16 + l15) * KD
                                          + kc * 64 + ks * 32 + quad * 8);
#pragma unroll
            for (int m = 0; m < 13; ++m) {
                frag af = *(const frag*)&As[buf][(m * 16 + l15) * 64
                                                + (((ks * 4 + quad) ^ (l15 & 7)) * 8)];
#pragma unroll
                for (int j = 0; j < 3; ++j)
                    acc[m][j] = __builtin_amdgcn_mfma_f32_16x16x32_bf16(af, bf[j], acc[m][j], 0, 0, 0);
            }
        }
        if (kc < 5 && stg) COMMIT(buf ^ 1);
        __syncthreads();
    }
#undef ISSUE
#undef COMMIT

    // ---- epilogue 1: tanh in place, per-row score partial per wave
    const float av0 = a_vec[wn + l15];
    const float av1 = a_vec[wn + 16 + l15];
    const float av2 = a_vec[wn + 32 + l15];

#pragma unroll
    for (int m = 0; m < 13; ++m) {
        float sct[4] = {0.f, 0.f, 0.f, 0.f};
#pragma unroll
        for (int j = 0; j < 3; ++j) {
            const float avj = (j == 0) ? av0 : ((j == 1) ? av1 : av2);
#pragma unroll
            for (int r = 0; r < 4; ++r) {
                const float hv = tanh_fast(acc[m][j][r]);
                acc[m][j][r] = hv;                 // keep h in registers
                sct[r] = fmaf(hv, avj, sct[r]);
            }
        }
#pragma unroll
        for (int r = 0; r < 4; ++r) {
            float v = sct[r];
            v += __shfl_xor(v, 1);
            v += __shfl_xor(v, 2);
            v += __shfl_xor(v, 4);
            v += __shfl_xor(v, 8);
            if (l15 == 0) sp[wave][m * 16 + quad * 4 + r] = v;
        }
    }
    __syncthreads();

    // ---- epilogue 2: softmax over the batch's 200 contexts (in-block)
    float e_t = 0.f;
    if (tid < MR) {
        const float s = sp[0][tid] + sp[1][tid] + sp[2][tid] + sp[3][tid]
                      + sp[4][tid] + sp[5][tid] + sp[6][tid] + sp[7][tid];
        score_s[tid] = (tid < CQ) ? s : -1e30f;
    }
    __syncthreads();
    if (wave == 0) {
        float v0 = score_s[lane], v1 = score_s[lane + 64], v2 = score_s[lane + 128];
        float v3 = (lane < MR - 192) ? score_s[lane + 192] : -1e30f;
        float mx = fmaxf(fmaxf(v0, v1), fmaxf(v2, v3));
#pragma unroll
        for (int o = 32; o; o >>= 1) mx = fmaxf(mx, __shfl_xor(mx, o));
        if (lane == 0) red_s[0] = mx;
    }
    __syncthreads();
    const float gm = red_s[0];
    if (tid < MR) {
        e_t = (tid < CQ) ? __expf(score_s[tid] - gm) : 0.f;
        score_s[tid] = e_t;
    }
    __syncthreads();
    if (wave == 0) {
        float v = score_s[lane] + score_s[lane + 64] + score_s[lane + 128]
                + ((lane < MR - 192) ? score_s[lane + 192] : 0.f);
#pragma unroll
        for (int o = 32; o; o >>= 1) v += __shfl_xor(v, o);
        if (lane == 0) red_s[1] = v;
    }
    __syncthreads();
    if (tid < MR) attn_s[tid] = e_t / red_s[1];
    __syncthreads();

    // ---- epilogue 3: attention-weighted sum -> out[b][v]
#pragma unroll
    for (int j = 0; j < 3; ++j) {
        float ws = 0.f;
#pragma unroll
        for (int m = 0; m < 13; ++m)
#pragma unroll
            for (int r = 0; r < 4; ++r)
                ws = fmaf(acc[m][j][r], attn_s[m * 16 + quad * 4 + r], ws);
        ws += __shfl_xor(ws, 16);
        ws += __shfl_xor(ws, 32);
        if (quad == 0) out[(size_t)b * CV + wn + j * 16 + l15] = ws;
    }
}

extern "C" void kernel_launch(void* const* d_in, const int* in_sizes, int n_in,
                              void* d_out, int out_size, void* d_ws, size_t ws_size,
                              hipStream_t stream) {
    const int*   starts   = (const int*)d_in[0];
    const int*   paths    = (const int*)d_in[1];
    const int*   ends     = (const int*)d_in[2];
    // d_in[3] = masks: unused (as in reference)
    const float* node_emb = (const float*)d_in[4];
    const float* path_emb = (const float*)d_in[5];
    const float* W        = (const float*)d_in[6];
    const float* a        = (const float*)d_in[7];
    float* out = (float*)d_out;

    // ws layout: Wb bf16 [CV*KD] only
    short* Wb = (short*)d_ws;

    conv_w<<<(CV * KD) / 1024, 256, 0, stream>>>(W, Wb);
    fused_all<<<BQ, 512, 0, stream>>>(starts, paths, ends, node_emb, path_emb,
                                      Wb, a, out);
}